// Round 14
// baseline (323.759 us; speedup 1.0000x reference)
//
#include <hip/hip_runtime.h>
#include <stdint.h>
#include <math.h>

typedef unsigned short u16;
typedef __bf16 bf16x8 __attribute__((ext_vector_type(8)));
typedef u16 u16x8 __attribute__((ext_vector_type(8)));
typedef u16 u16x4 __attribute__((ext_vector_type(4)));
typedef float f32x4 __attribute__((ext_vector_type(4)));

#define NEG_ -10000.0f

__device__ __forceinline__ u16 f2bf(float f){
  unsigned u = __float_as_uint(f);
  unsigned r = (u + 0x7fffu + ((u >> 16) & 1u)) >> 16;
  return (u16)r;
}
__device__ __forceinline__ float bf2f(u16 v){
  return __uint_as_float(((unsigned)v) << 16);
}

// gelu exact via Abramowitz-Stegun 7.1.26 erf (|err| < 1.5e-7), ~14 VALU ops
__device__ __forceinline__ float gelu_exact(float v){
  float xe = v * 0.70710678118654752f;
  float ax = fabsf(xe);
  float k  = 1.0f / (1.0f + 0.3275911f * ax);
  float p  = ((((1.061405429f * k - 1.453152027f) * k + 1.421413741f) * k
               - 0.284496736f) * k + 0.254829592f) * k;
  float er = 1.0f - p * __expf(-ax * ax);
  er = copysignf(er, xe);
  return 0.5f * v * (1.0f + er);
}
__device__ __forceinline__ float sigmoidf_(float z){ return 1.f / (1.f + expf(-z)); }

__device__ __forceinline__ void async_load16(const void* g, void* lds){
  typedef const __attribute__((address_space(1))) unsigned int* gp_t;
  typedef __attribute__((address_space(3))) unsigned int* lp_t;
  __builtin_amdgcn_global_load_lds((gp_t)(uintptr_t)g, (lp_t)(uintptr_t)lds, 16, 0, 0);
}

__device__ __forceinline__ unsigned swz(unsigned o){ return o ^ ((o >> 3) & 0x70u); }

// ---------------- fused prep: gates + both weight conversions (one launch) ------------
__global__ __launch_bounds__(256) void prep_all(
    const float* __restrict__ s, const int* __restrict__ t,
    const float* __restrict__ efc1, const float* __restrict__ efc2,
    const float* __restrict__ elarger, const float* __restrict__ fc1_b,
    const float* __restrict__ fc1_w, const float* __restrict__ fc2_w,
    float* __restrict__ gfc1p, float* __restrict__ b1p,
    float* __restrict__ gfc2, float* __restrict__ glarger,
    u16* __restrict__ Bw1, u16* __restrict__ Bw2)
{
  const int b = blockIdx.x;
  const int tid = threadIdx.x;
  if (b < 1536){                                     // conv_w1: [2048][768]
    int q = b * 256 + tid;
    int idx = q * 4;
    int n = idx / 768, k = idx % 768;
    ushort4 o;
    if (n < 2000){
      float4 v = *(const float4*)(fc1_w + (size_t)n * 768 + k);
      o.x = f2bf(v.x); o.y = f2bf(v.y); o.z = f2bf(v.z); o.w = f2bf(v.w);
    } else { o.x = o.y = o.z = o.w = 0; }
    *(ushort4*)(Bw1 + idx) = o;
  } else if (b < 3072){                              // conv_w2: [768][2048]
    int q = (b - 1536) * 256 + tid;
    int idx = q * 4;
    int h = idx / 2048, k = idx % 2048;
    ushort4 o;
    if (k < 2000){
      float4 v = *(const float4*)(fc2_w + (size_t)h * 2000 + k);
      o.x = f2bf(v.x); o.y = f2bf(v.y); o.z = f2bf(v.z); o.w = f2bf(v.w);
    } else { o.x = o.y = o.z = o.w = 0; }
    *(ushort4*)(Bw2 + idx) = o;
  } else {                                           // gates + padded bias
    int i = (b - 3072) * 256 + tid;
    float sv = s[0]; int tt = t[0];
    if (i < 2048){
      float g = 0.f, bb = 0.f;
      if (i < 2000){ g = sigmoidf_(sv * efc1[tt * 2000 + i]); bb = fc1_b[i]; }
      gfc1p[i] = g; b1p[i] = bb;
    }
    if (i < 768){
      gfc2[i]    = sigmoidf_(sv * efc2[tt * 768 + i]);
      glarger[i] = sigmoidf_(sv * elarger[tt * 768 + i]);
    }
  }
}

// ---------------- sem capsules (MFMA) + squash + routing + hpre, fully fused ----------
// (unchanged from R8-R13 — passing)
__global__ __launch_bounds__(256) void sem_route(
    const float* __restrict__ x, const int* __restrict__ t_ptr,
    const float* __restrict__ sem_w, const float* __restrict__ sem_b,
    const float* __restrict__ rw, const float* __restrict__ larger_w,
    const float* __restrict__ larger_b, const float* __restrict__ glarger,
    u16* __restrict__ hpre)
{
  __shared__ __align__(16) u16 xbf[12 * 32 * 64];   // 49152 B, 12 subtiles of [32][64]
  __shared__ __align__(16) u16 wlds[2 * 32 * 64];   //  8192 B, double-buffered [32][64]
  __shared__ float semv_s[32][32];                  //  4096 B
  __shared__ float votes_s[32][9];                  //  1152 B

  const int tid  = (int)threadIdx.x;
  const int w    = tid >> 6, l = tid & 63;
  const int tok0 = (int)blockIdx.x * 32;

  {
    const int r = tid >> 3;            // 0..31 token row
    const int kq = (tid & 7) * 8;      // 8 k-elems
    const float* xrow = x + (size_t)(tok0 + r) * 768 + kq;
#pragma unroll
    for (int j = 0; j < 12; ++j){
      float4 v0 = *(const float4*)(xrow + j * 64);
      float4 v1 = *(const float4*)(xrow + j * 64 + 4);
      u16x8 pk;
      pk[0] = f2bf(v0.x); pk[1] = f2bf(v0.y); pk[2] = f2bf(v0.z); pk[3] = f2bf(v0.w);
      pk[4] = f2bf(v1.x); pk[5] = f2bf(v1.y); pk[6] = f2bf(v1.z); pk[7] = f2bf(v1.w);
      unsigned o = (unsigned)(((j * 32 + r) << 7) + kq * 2);
      *(u16x8*)((char*)xbf + swz(o)) = pk;
    }
    u16x8 pw = (u16x8)(u16)0;
    if (r < 30){
      const float* wr_ = sem_w + (size_t)r * 768 + kq;
      float4 v0 = *(const float4*)(wr_);
      float4 v1 = *(const float4*)(wr_ + 4);
      pw[0] = f2bf(v0.x); pw[1] = f2bf(v0.y); pw[2] = f2bf(v0.z); pw[3] = f2bf(v0.w);
      pw[4] = f2bf(v1.x); pw[5] = f2bf(v1.y); pw[6] = f2bf(v1.z); pw[7] = f2bf(v1.w);
    }
    unsigned ow = (unsigned)((r << 7) + kq * 2);
    *(u16x8*)((char*)wlds + swz(ow)) = pw;
  }
  __syncthreads();

  const int rowblk = (w >> 1) * 16, nb = (w & 1) * 16;
  f32x4 acc = (f32x4){0.f, 0.f, 0.f, 0.f};
  for (int j = 0; j < 12; ++j){
    const int buf = j & 1;
    bf16x8 af[2], bf[2];
#pragma unroll
    for (int ks = 0; ks < 2; ++ks){
      unsigned oa = (unsigned)(((j * 32 + rowblk + (l & 15)) << 7) + ks * 64 + ((l >> 4) << 4));
      af[ks] = *(const bf16x8*)((const char*)xbf + swz(oa));
      unsigned ob = (unsigned)(((buf * 32 + nb + (l & 15)) << 7) + ks * 64 + ((l >> 4) << 4));
      bf[ks] = *(const bf16x8*)((const char*)wlds + swz(ob));
    }
    if (j + 1 < 12){
      const int r = tid >> 3, kq = (tid & 7) * 8;
      u16x8 pw = (u16x8)(u16)0;
      if (r < 30){
        const float* wr_ = sem_w + (size_t)r * 768 + (j + 1) * 64 + kq;
        float4 v0 = *(const float4*)(wr_);
        float4 v1 = *(const float4*)(wr_ + 4);
        pw[0] = f2bf(v0.x); pw[1] = f2bf(v0.y); pw[2] = f2bf(v0.z); pw[3] = f2bf(v0.w);
        pw[4] = f2bf(v1.x); pw[5] = f2bf(v1.y); pw[6] = f2bf(v1.z); pw[7] = f2bf(v1.w);
      }
      unsigned ow = (unsigned)(((((j + 1) & 1) * 32 + r) << 7) + kq * 2);
      *(u16x8*)((char*)wlds + swz(ow)) = pw;
    }
#pragma unroll
    for (int ks = 0; ks < 2; ++ks)
      acc = __builtin_amdgcn_mfma_f32_16x16x32_bf16(af[ks], bf[ks], acc, 0, 0, 0);
    __syncthreads();
  }
#pragma unroll
  for (int jj = 0; jj < 4; ++jj)
    semv_s[rowblk + (l >> 4) * 4 + jj][nb + (l & 15)] = acc[jj];
  __syncthreads();

  if (tid < 96){
    const int tk = tid & 31, m = tid >> 5;
    const int tt = t_ptr[0];
    float s30[30];
#pragma unroll
    for (int jf = 0; jf < 30; ++jf){
      const int c = jf / 10, tcap = jf % 10;
      const int wrow = tcap * 3 + c;
      s30[jf] = semv_s[tk][wrow] + sem_b[wrow];
    }
#pragma unroll
    for (int c = 0; c < 3; ++c){
      float sq = 0.f;
#pragma unroll
      for (int jf = 0; jf < 10; ++jf){ float v = s30[c * 10 + jf]; sq += v * v; }
      sq += 1e-16f;
      const float scale = (sq / (1.f + sq)) / sqrtf(sq);
#pragma unroll
      for (int jf = 0; jf < 10; ++jf) s30[c * 10 + jf] *= scale;
    }
    float p[10][3];
#pragma unroll
    for (int r = 0; r < 10; r++){
      const float x0 = s30[r * 3 + 0], x1 = s30[r * 3 + 1], x2 = s30[r * 3 + 2];
      const float* rwp = rw + m * 90 + r * 9;
#pragma unroll
      for (int d = 0; d < 3; d++)
        p[r][d] = x0 * rwp[d] + x1 * rwp[3 + d] + x2 * rwp[6 + d];
    }
    float lg[10];
#pragma unroll
    for (int r = 0; r < 10; r++) lg[r] = 0.f;
    float v0 = 0.f, v1 = 0.f, v2 = 0.f;
    for (int it = 0; it < 3; ++it){
      float lr[10]; float mx = -3.0e38f;
#pragma unroll
      for (int r = 0; r < 10; r++){ lr[r] = (r <= tt) ? lg[r] : NEG_; mx = fmaxf(mx, lr[r]); }
      float e[10]; float sum = 0.f;
#pragma unroll
      for (int r = 0; r < 10; r++){ e[r] = expf(lr[r] - mx); sum += e[r]; }
      const float inv = 1.f / sum;
      v0 = 0.f; v1 = 0.f; v2 = 0.f;
#pragma unroll
      for (int r = 0; r < 10; r++){
        const float pr = e[r] * inv;
        v0 += pr * p[r][0]; v1 += pr * p[r][1]; v2 += pr * p[r][2];
      }
      if (it < 2){
        float sq = v0 * v0 + v1 * v1 + v2 * v2 + 1e-16f;
        float scale = (sq / (1.f + sq)) / sqrtf(sq);
        const float o0 = v0 * scale, o1 = v1 * scale, o2 = v2 * scale;
#pragma unroll
        for (int r = 0; r < 10; r++) lg[r] += p[r][0] * o0 + p[r][1] * o1 + p[r][2] * o2;
      }
    }
    votes_s[tk][m * 3 + 0] = v0;
    votes_s[tk][m * 3 + 1] = v1;
    votes_s[tk][m * 3 + 2] = v2;
  }
  __syncthreads();

  if (tid < 192){
    const int q = tid, h0 = q * 4;
    float lw36[36];
    const float4* lwq = (const float4*)(larger_w + (size_t)h0 * 9);
#pragma unroll
    for (int k = 0; k < 9; k++){
      float4 tq = lwq[k];
      lw36[4*k] = tq.x; lw36[4*k+1] = tq.y; lw36[4*k+2] = tq.z; lw36[4*k+3] = tq.w;
    }
    const float4 bq = *(const float4*)(larger_b + h0);
    const float4 gq = *(const float4*)(glarger + h0);
    const float bb[4] = {bq.x, bq.y, bq.z, bq.w};
    const float gg[4] = {gq.x, gq.y, gq.z, gq.w};
    const int kstep = h0 >> 6, col = h0 & 63;
    for (int tk = 0; tk < 32; ++tk){
      float vt[9];
#pragma unroll
      for (int k = 0; k < 9; k++) vt[k] = votes_s[tk][k];
      unsigned o = (unsigned)(((kstep * 32 + tk) << 7) + col * 2);
      u16x4 xb = *(const u16x4*)((const char*)xbf + swz(o));
      u16 oa[4];
#pragma unroll
      for (int r = 0; r < 4; ++r){
        float a = bb[r];
#pragma unroll
        for (int k = 0; k < 9; ++k) a += vt[k] * lw36[r * 9 + k];
        oa[r] = f2bf(bf2f(xb[r]) + a * gg[r]);
      }
      ushort4 ov; ov.x = oa[0]; ov.y = oa[1]; ov.z = oa[2]; ov.w = oa[3];
      *(ushort4*)(hpre + (size_t)(tok0 + tk) * 768 + h0) = ov;
    }
  }
}

// ---------------- 128x128 bf16 MFMA GEMM, m97-simple structure + T2 swizzle -------------
// R13 base (73.7 us/GEMM, MfmaUtil 30%) + two bounded changes:
//  (1) ds_read addressing: swz(base+fi*2048) == swz(base)+fi*2048 (fi bits >=11 don't
//      interact with the XOR at bits 4-6; correction is (l&7)<<4, lane-only). ks*64 does
//      NOT commute (bit-6 carry when l&4), so 2 bases per operand (ks=0/1). 4 hoisted
//      unsigneds -> all 16 reads become vaddr + compile-time immediate. Replaces ~16
//      recomputed addresses (fewer live temps than before -> no spill risk).
//  (2) setprio(1) around the MFMA cluster: 4 desynced blocks/CU = wave role diversity
//      (T5's prerequisite). Revert if it shows the m190 sign.
// MODE 0: store bf16(gelu(acc+bias)*gate);  MODE 1: store f32 xres + gelu(acc+bias)*gate.
template<int MODE, int NDIM, int KDIM>
__global__ __launch_bounds__(256, 4) void gemm128(
    const u16* __restrict__ A, const u16* __restrict__ B,
    const float* __restrict__ bias, const float* __restrict__ gate,
    const float* __restrict__ xres, void* __restrict__ Cout, int NT_N)
{
  __shared__ __align__(16) u16 As[8192];   // 128 rows x 64 k
  __shared__ __align__(16) u16 Bs[8192];
  constexpr int NT = KDIM / 64;

  const int nwg = (int)gridDim.x;              // multiple of 8
  const int cpx = nwg >> 3;
  const int wg  = ((int)blockIdx.x & 7) * cpx + ((int)blockIdx.x >> 3);
  const int bm = wg / NT_N, bn = wg % NT_N;
  const int m0 = bm * 128, n0 = bn * 128;
  const int tid = (int)threadIdx.x;
  const int w = tid >> 6, l = tid & 63;
  const int wr = w >> 1, wc = w & 1;           // 2 x 2 wave grid; wave tile 64 x 64

  f32x4 acc[4][4];
#pragma unroll
  for (int i = 0; i < 4; i++)
#pragma unroll
    for (int j = 0; j < 4; j++)
      acc[i][j] = (f32x4){0.f, 0.f, 0.f, 0.f};

  // hoisted swizzled read bases (loop-invariant; fi folds to an immediate)
  const unsigned aB0 = swz((unsigned)(((wr * 64 + (l & 15)) << 7) + ((l >> 4) << 4)));
  const unsigned aB1 = swz((unsigned)(((wr * 64 + (l & 15)) << 7) + 64 + ((l >> 4) << 4)));
  const unsigned bB0 = swz((unsigned)(((wc * 64 + (l & 15)) << 7) + ((l >> 4) << 4)));
  const unsigned bB1 = swz((unsigned)(((wc * 64 + (l & 15)) << 7) + 64 + ((l >> 4) << 4)));

  // stage one 128x64 tile (16KB): linear LDS dest, swizzled global source (rule #21)
  auto stage_tile = [&](const u16* __restrict__ src, int r0, int k0, u16* lds){
#pragma unroll
    for (int jj = 0; jj < 4; ++jj){
      unsigned o  = (unsigned)(jj * 4096 + tid * 16);
      unsigned lo = swz(o);
      const u16* g = src + (size_t)(r0 + (int)(lo >> 7)) * KDIM + (k0 + (int)((lo & 127u) >> 1));
      async_load16(g, (char*)lds + jj * 4096 + w * 1024);
    }
  };

  for (int j = 0; j < NT; ++j){
    stage_tile(A, m0, j * 64, As);
    stage_tile(B, n0, j * 64, Bs);
    __syncthreads();                            // drains vmcnt; staged data visible
    bf16x8 afr[4][2], bfr[4][2];
#pragma unroll
    for (int fi = 0; fi < 4; ++fi){
      afr[fi][0] = *(const bf16x8*)((const char*)As + aB0 + fi * 2048);
      afr[fi][1] = *(const bf16x8*)((const char*)As + aB1 + fi * 2048);
      bfr[fi][0] = *(const bf16x8*)((const char*)Bs + bB0 + fi * 2048);
      bfr[fi][1] = *(const bf16x8*)((const char*)Bs + bB1 + fi * 2048);
    }
    __builtin_amdgcn_s_setprio(1);
#pragma unroll
    for (int ks = 0; ks < 2; ++ks)
#pragma unroll
      for (int fi = 0; fi < 4; ++fi)
#pragma unroll
        for (int g = 0; g < 4; ++g)
          acc[fi][g] = __builtin_amdgcn_mfma_f32_16x16x32_bf16(
              afr[fi][ks], bfr[g][ks], acc[fi][g], 0, 0, 0);
    __builtin_amdgcn_s_setprio(0);
    __syncthreads();                            // all waves done reading before restage
  }

  // epilogue
#pragma unroll
  for (int f = 0; f < 4; ++f){
    const int rowb = m0 + wr * 64 + f * 16 + ((l >> 4) << 2);
#pragma unroll
    for (int g = 0; g < 4; ++g){
      const int col = n0 + wc * 64 + g * 16 + (l & 15);
      const float bv = bias[col], gv = gate[col];
#pragma unroll
      for (int j = 0; j < 4; ++j){
        const int row = rowb + j;
        float v = acc[f][g][j] + bv;
        float gl = gelu_exact(v) * gv;
        if (MODE == 0){
          ((u16*)Cout)[(size_t)row * NDIM + col] = f2bf(gl);
        } else {
          size_t off = (size_t)row * NDIM + col;
          ((float*)Cout)[off] = xres[off] + gl;
        }
      }
    }
  }
}

// ---------------- launcher ----------------
extern "C" void kernel_launch(void* const* d_in, const int* in_sizes, int n_in,
                              void* d_out, int out_size, void* d_ws, size_t ws_size,
                              hipStream_t stream)
{
  const float* x       = (const float*)d_in[0];
  const int*   t       = (const int*)  d_in[1];
  const float* s       = (const float*)d_in[2];
  const float* fc1_w   = (const float*)d_in[3];
  const float* fc1_b   = (const float*)d_in[4];
  const float* fc2_w   = (const float*)d_in[5];
  const float* fc2_b   = (const float*)d_in[6];
  const float* efc1    = (const float*)d_in[7];
  const float* efc2    = (const float*)d_in[8];
  const float* sem_w   = (const float*)d_in[9];
  const float* sem_b   = (const float*)d_in[10];
  const float* rw      = (const float*)d_in[11];
  const float* larger_w= (const float*)d_in[12];
  const float* larger_b= (const float*)d_in[13];
  const float* elarger = (const float*)d_in[14];

  char* ws = (char*)d_ws;
  float* gfc1p   = (float*)(ws + 0);         //    8192 B  [2048]
  float* b1p     = (float*)(ws + 8192);      //    8192 B  [2048]
  float* gfc2    = (float*)(ws + 16384);     //    3072 B  [768]
  float* glarger = (float*)(ws + 19456);     //    3072 B  [768]
  u16*   Bw1     = (u16*)  (ws + 22528);     // 3145728 B  [2048][768] bf16
  u16*   Bw2     = (u16*)  (ws + 3168256);   // 3145728 B  [768][2048] bf16
  u16*   hpre    = (u16*)  (ws + 6313984);   // 25165824 B [16384][768] bf16
  u16*   Hm      = (u16*)  (ws + 31479808);  // 67108864 B [16384][2048] bf16
  // total 98,588,672 B

  prep_all<<<3080, 256, 0, stream>>>(s, t, efc1, efc2, elarger, fc1_b, fc1_w, fc2_w,
                                     gfc1p, b1p, gfc2, glarger, Bw1, Bw2);
  sem_route<<<512, 256, 0, stream>>>(x, t, sem_w, sem_b, rw, larger_w, larger_b, glarger, hpre);
  gemm128<0, 2048, 768><<<2048, 256, 0, stream>>>(hpre, Bw1, b1p, gfc1p, nullptr, (void*)Hm, 16);
  gemm128<1, 768, 2048><<<768, 256, 0, stream>>>(Hm, Bw2, fc2_b, gfc2, x, d_out, 6);
}

// Round 15
// 172.428 us; speedup vs baseline: 1.8776x; 1.8776x over previous
//
#include <hip/hip_runtime.h>
#include <stdint.h>
#include <math.h>

typedef unsigned short u16;
typedef __bf16 bf16x8 __attribute__((ext_vector_type(8)));
typedef u16 u16x8 __attribute__((ext_vector_type(8)));
typedef u16 u16x4 __attribute__((ext_vector_type(4)));
typedef float f32x4 __attribute__((ext_vector_type(4)));

#define NEG_ -10000.0f

__device__ __forceinline__ u16 f2bf(float f){
  unsigned u = __float_as_uint(f);
  unsigned r = (u + 0x7fffu + ((u >> 16) & 1u)) >> 16;
  return (u16)r;
}
__device__ __forceinline__ float bf2f(u16 v){
  return __uint_as_float(((unsigned)v) << 16);
}

// gelu exact via Abramowitz-Stegun 7.1.26 erf (|err| < 1.5e-7), ~14 VALU ops
__device__ __forceinline__ float gelu_exact(float v){
  float xe = v * 0.70710678118654752f;
  float ax = fabsf(xe);
  float k  = 1.0f / (1.0f + 0.3275911f * ax);
  float p  = ((((1.061405429f * k - 1.453152027f) * k + 1.421413741f) * k
               - 0.284496736f) * k + 0.254829592f) * k;
  float er = 1.0f - p * __expf(-ax * ax);
  er = copysignf(er, xe);
  return 0.5f * v * (1.0f + er);
}
__device__ __forceinline__ float sigmoidf_(float z){ return 1.f / (1.f + expf(-z)); }

__device__ __forceinline__ void async_load16(const void* g, void* lds){
  typedef const __attribute__((address_space(1))) unsigned int* gp_t;
  typedef __attribute__((address_space(3))) unsigned int* lp_t;
  __builtin_amdgcn_global_load_lds((gp_t)(uintptr_t)g, (lp_t)(uintptr_t)lds, 16, 0, 0);
}

__device__ __forceinline__ unsigned swz(unsigned o){ return o ^ ((o >> 3) & 0x70u); }

// ---------------- fused prep: gates + both weight conversions (one launch) ------------
__global__ __launch_bounds__(256) void prep_all(
    const float* __restrict__ s, const int* __restrict__ t,
    const float* __restrict__ efc1, const float* __restrict__ efc2,
    const float* __restrict__ elarger, const float* __restrict__ fc1_b,
    const float* __restrict__ fc1_w, const float* __restrict__ fc2_w,
    float* __restrict__ gfc1p, float* __restrict__ b1p,
    float* __restrict__ gfc2, float* __restrict__ glarger,
    u16* __restrict__ Bw1, u16* __restrict__ Bw2)
{
  const int b = blockIdx.x;
  const int tid = threadIdx.x;
  if (b < 1536){                                     // conv_w1: [2048][768]
    int q = b * 256 + tid;
    int idx = q * 4;
    int n = idx / 768, k = idx % 768;
    ushort4 o;
    if (n < 2000){
      float4 v = *(const float4*)(fc1_w + (size_t)n * 768 + k);
      o.x = f2bf(v.x); o.y = f2bf(v.y); o.z = f2bf(v.z); o.w = f2bf(v.w);
    } else { o.x = o.y = o.z = o.w = 0; }
    *(ushort4*)(Bw1 + idx) = o;
  } else if (b < 3072){                              // conv_w2: [768][2048]
    int q = (b - 1536) * 256 + tid;
    int idx = q * 4;
    int h = idx / 2048, k = idx % 2048;
    ushort4 o;
    if (k < 2000){
      float4 v = *(const float4*)(fc2_w + (size_t)h * 2000 + k);
      o.x = f2bf(v.x); o.y = f2bf(v.y); o.z = f2bf(v.z); o.w = f2bf(v.w);
    } else { o.x = o.y = o.z = o.w = 0; }
    *(ushort4*)(Bw2 + idx) = o;
  } else {                                           // gates + padded bias
    int i = (b - 3072) * 256 + tid;
    float sv = s[0]; int tt = t[0];
    if (i < 2048){
      float g = 0.f, bb = 0.f;
      if (i < 2000){ g = sigmoidf_(sv * efc1[tt * 2000 + i]); bb = fc1_b[i]; }
      gfc1p[i] = g; b1p[i] = bb;
    }
    if (i < 768){
      gfc2[i]    = sigmoidf_(sv * efc2[tt * 768 + i]);
      glarger[i] = sigmoidf_(sv * elarger[tt * 768 + i]);
    }
  }
}

// ---------------- sem capsules (MFMA) + squash + routing + hpre, fully fused ----------
// (unchanged from R8-R13 — passing)
__global__ __launch_bounds__(256) void sem_route(
    const float* __restrict__ x, const int* __restrict__ t_ptr,
    const float* __restrict__ sem_w, const float* __restrict__ sem_b,
    const float* __restrict__ rw, const float* __restrict__ larger_w,
    const float* __restrict__ larger_b, const float* __restrict__ glarger,
    u16* __restrict__ hpre)
{
  __shared__ __align__(16) u16 xbf[12 * 32 * 64];   // 49152 B, 12 subtiles of [32][64]
  __shared__ __align__(16) u16 wlds[2 * 32 * 64];   //  8192 B, double-buffered [32][64]
  __shared__ float semv_s[32][32];                  //  4096 B
  __shared__ float votes_s[32][9];                  //  1152 B

  const int tid  = (int)threadIdx.x;
  const int w    = tid >> 6, l = tid & 63;
  const int tok0 = (int)blockIdx.x * 32;

  {
    const int r = tid >> 3;            // 0..31 token row
    const int kq = (tid & 7) * 8;      // 8 k-elems
    const float* xrow = x + (size_t)(tok0 + r) * 768 + kq;
#pragma unroll
    for (int j = 0; j < 12; ++j){
      float4 v0 = *(const float4*)(xrow + j * 64);
      float4 v1 = *(const float4*)(xrow + j * 64 + 4);
      u16x8 pk;
      pk[0] = f2bf(v0.x); pk[1] = f2bf(v0.y); pk[2] = f2bf(v0.z); pk[3] = f2bf(v0.w);
      pk[4] = f2bf(v1.x); pk[5] = f2bf(v1.y); pk[6] = f2bf(v1.z); pk[7] = f2bf(v1.w);
      unsigned o = (unsigned)(((j * 32 + r) << 7) + kq * 2);
      *(u16x8*)((char*)xbf + swz(o)) = pk;
    }
    u16x8 pw = (u16x8)(u16)0;
    if (r < 30){
      const float* wr_ = sem_w + (size_t)r * 768 + kq;
      float4 v0 = *(const float4*)(wr_);
      float4 v1 = *(const float4*)(wr_ + 4);
      pw[0] = f2bf(v0.x); pw[1] = f2bf(v0.y); pw[2] = f2bf(v0.z); pw[3] = f2bf(v0.w);
      pw[4] = f2bf(v1.x); pw[5] = f2bf(v1.y); pw[6] = f2bf(v1.z); pw[7] = f2bf(v1.w);
    }
    unsigned ow = (unsigned)((r << 7) + kq * 2);
    *(u16x8*)((char*)wlds + swz(ow)) = pw;
  }
  __syncthreads();

  const int rowblk = (w >> 1) * 16, nb = (w & 1) * 16;
  f32x4 acc = (f32x4){0.f, 0.f, 0.f, 0.f};
  for (int j = 0; j < 12; ++j){
    const int buf = j & 1;
    bf16x8 af[2], bf[2];
#pragma unroll
    for (int ks = 0; ks < 2; ++ks){
      unsigned oa = (unsigned)(((j * 32 + rowblk + (l & 15)) << 7) + ks * 64 + ((l >> 4) << 4));
      af[ks] = *(const bf16x8*)((const char*)xbf + swz(oa));
      unsigned ob = (unsigned)(((buf * 32 + nb + (l & 15)) << 7) + ks * 64 + ((l >> 4) << 4));
      bf[ks] = *(const bf16x8*)((const char*)wlds + swz(ob));
    }
    if (j + 1 < 12){
      const int r = tid >> 3, kq = (tid & 7) * 8;
      u16x8 pw = (u16x8)(u16)0;
      if (r < 30){
        const float* wr_ = sem_w + (size_t)r * 768 + (j + 1) * 64 + kq;
        float4 v0 = *(const float4*)(wr_);
        float4 v1 = *(const float4*)(wr_ + 4);
        pw[0] = f2bf(v0.x); pw[1] = f2bf(v0.y); pw[2] = f2bf(v0.z); pw[3] = f2bf(v0.w);
        pw[4] = f2bf(v1.x); pw[5] = f2bf(v1.y); pw[6] = f2bf(v1.z); pw[7] = f2bf(v1.w);
      }
      unsigned ow = (unsigned)(((((j + 1) & 1) * 32 + r) << 7) + kq * 2);
      *(u16x8*)((char*)wlds + swz(ow)) = pw;
    }
#pragma unroll
    for (int ks = 0; ks < 2; ++ks)
      acc = __builtin_amdgcn_mfma_f32_16x16x32_bf16(af[ks], bf[ks], acc, 0, 0, 0);
    __syncthreads();
  }
#pragma unroll
  for (int jj = 0; jj < 4; ++jj)
    semv_s[rowblk + (l >> 4) * 4 + jj][nb + (l & 15)] = acc[jj];
  __syncthreads();

  if (tid < 96){
    const int tk = tid & 31, m = tid >> 5;
    const int tt = t_ptr[0];
    float s30[30];
#pragma unroll
    for (int jf = 0; jf < 30; ++jf){
      const int c = jf / 10, tcap = jf % 10;
      const int wrow = tcap * 3 + c;
      s30[jf] = semv_s[tk][wrow] + sem_b[wrow];
    }
#pragma unroll
    for (int c = 0; c < 3; ++c){
      float sq = 0.f;
#pragma unroll
      for (int jf = 0; jf < 10; ++jf){ float v = s30[c * 10 + jf]; sq += v * v; }
      sq += 1e-16f;
      const float scale = (sq / (1.f + sq)) / sqrtf(sq);
#pragma unroll
      for (int jf = 0; jf < 10; ++jf) s30[c * 10 + jf] *= scale;
    }
    float p[10][3];
#pragma unroll
    for (int r = 0; r < 10; r++){
      const float x0 = s30[r * 3 + 0], x1 = s30[r * 3 + 1], x2 = s30[r * 3 + 2];
      const float* rwp = rw + m * 90 + r * 9;
#pragma unroll
      for (int d = 0; d < 3; d++)
        p[r][d] = x0 * rwp[d] + x1 * rwp[3 + d] + x2 * rwp[6 + d];
    }
    float lg[10];
#pragma unroll
    for (int r = 0; r < 10; r++) lg[r] = 0.f;
    float v0 = 0.f, v1 = 0.f, v2 = 0.f;
    for (int it = 0; it < 3; ++it){
      float lr[10]; float mx = -3.0e38f;
#pragma unroll
      for (int r = 0; r < 10; r++){ lr[r] = (r <= tt) ? lg[r] : NEG_; mx = fmaxf(mx, lr[r]); }
      float e[10]; float sum = 0.f;
#pragma unroll
      for (int r = 0; r < 10; r++){ e[r] = expf(lr[r] - mx); sum += e[r]; }
      const float inv = 1.f / sum;
      v0 = 0.f; v1 = 0.f; v2 = 0.f;
#pragma unroll
      for (int r = 0; r < 10; r++){
        const float pr = e[r] * inv;
        v0 += pr * p[r][0]; v1 += pr * p[r][1]; v2 += pr * p[r][2];
      }
      if (it < 2){
        float sq = v0 * v0 + v1 * v1 + v2 * v2 + 1e-16f;
        float scale = (sq / (1.f + sq)) / sqrtf(sq);
        const float o0 = v0 * scale, o1 = v1 * scale, o2 = v2 * scale;
#pragma unroll
        for (int r = 0; r < 10; r++) lg[r] += p[r][0] * o0 + p[r][1] * o1 + p[r][2] * o2;
      }
    }
    votes_s[tk][m * 3 + 0] = v0;
    votes_s[tk][m * 3 + 1] = v1;
    votes_s[tk][m * 3 + 2] = v2;
  }
  __syncthreads();

  if (tid < 192){
    const int q = tid, h0 = q * 4;
    float lw36[36];
    const float4* lwq = (const float4*)(larger_w + (size_t)h0 * 9);
#pragma unroll
    for (int k = 0; k < 9; k++){
      float4 tq = lwq[k];
      lw36[4*k] = tq.x; lw36[4*k+1] = tq.y; lw36[4*k+2] = tq.z; lw36[4*k+3] = tq.w;
    }
    const float4 bq = *(const float4*)(larger_b + h0);
    const float4 gq = *(const float4*)(glarger + h0);
    const float bb[4] = {bq.x, bq.y, bq.z, bq.w};
    const float gg[4] = {gq.x, gq.y, gq.z, gq.w};
    const int kstep = h0 >> 6, col = h0 & 63;
    for (int tk = 0; tk < 32; ++tk){
      float vt[9];
#pragma unroll
      for (int k = 0; k < 9; k++) vt[k] = votes_s[tk][k];
      unsigned o = (unsigned)(((kstep * 32 + tk) << 7) + col * 2);
      u16x4 xb = *(const u16x4*)((const char*)xbf + swz(o));
      u16 oa[4];
#pragma unroll
      for (int r = 0; r < 4; ++r){
        float a = bb[r];
#pragma unroll
        for (int k = 0; k < 9; ++k) a += vt[k] * lw36[r * 9 + k];
        oa[r] = f2bf(bf2f(xb[r]) + a * gg[r]);
      }
      ushort4 ov; ov.x = oa[0]; ov.y = oa[1]; ov.z = oa[2]; ov.w = oa[3];
      *(ushort4*)(hpre + (size_t)(tok0 + tk) * 768 + h0) = ov;
    }
  }
}

// ---------------- 128x128 bf16 MFMA GEMM, m97-simple structure + T2 swizzle -------------
// EXACT R11/R13 form (73.7 us/GEMM, MfmaUtil 30%, 0 bank conflicts, no scratch).
// Post-mortem ledger of failed "improvements" to this loop — do not repeat:
//  R10: B direct-from-global (L2 not stable under streaming) -> 2x slower.
//  R12: pointer-array hoisting -> scratch spill (WRITE 237 MB) -> 2x slower.
//  R14: hoisted bases + setprio fence widened frag live ranges past the 128-VGPR
//       tier (launch_bounds(256,4)) -> scratch spill (WRITE 306 MB) -> 2x slower.
// The inline address recompute + free scheduler interleave is what keeps live state
// under the occupancy-tier register budget.
// MODE 0: store bf16(gelu(acc+bias)*gate);  MODE 1: store f32 xres + gelu(acc+bias)*gate.
template<int MODE, int NDIM, int KDIM>
__global__ __launch_bounds__(256, 4) void gemm128(
    const u16* __restrict__ A, const u16* __restrict__ B,
    const float* __restrict__ bias, const float* __restrict__ gate,
    const float* __restrict__ xres, void* __restrict__ Cout, int NT_N)
{
  __shared__ __align__(16) u16 As[8192];   // 128 rows x 64 k
  __shared__ __align__(16) u16 Bs[8192];
  constexpr int NT = KDIM / 64;

  const int nwg = (int)gridDim.x;              // multiple of 8
  const int cpx = nwg >> 3;
  const int wg  = ((int)blockIdx.x & 7) * cpx + ((int)blockIdx.x >> 3);
  const int bm = wg / NT_N, bn = wg % NT_N;
  const int m0 = bm * 128, n0 = bn * 128;
  const int tid = (int)threadIdx.x;
  const int w = tid >> 6, l = tid & 63;
  const int wr = w >> 1, wc = w & 1;           // 2 x 2 wave grid; wave tile 64 x 64

  f32x4 acc[4][4];
#pragma unroll
  for (int i = 0; i < 4; i++)
#pragma unroll
    for (int j = 0; j < 4; j++)
      acc[i][j] = (f32x4){0.f, 0.f, 0.f, 0.f};

  // stage one 128x64 tile (16KB): linear LDS dest, swizzled global source (rule #21)
  auto stage_tile = [&](const u16* __restrict__ src, int r0, int k0, u16* lds){
#pragma unroll
    for (int jj = 0; jj < 4; ++jj){
      unsigned o  = (unsigned)(jj * 4096 + tid * 16);
      unsigned lo = swz(o);
      const u16* g = src + (size_t)(r0 + (int)(lo >> 7)) * KDIM + (k0 + (int)((lo & 127u) >> 1));
      async_load16(g, (char*)lds + jj * 4096 + w * 1024);
    }
  };

  for (int j = 0; j < NT; ++j){
    stage_tile(A, m0, j * 64, As);
    stage_tile(B, n0, j * 64, Bs);
    __syncthreads();                            // drains vmcnt; staged data visible
    bf16x8 afr[4][2], bfr[4][2];
#pragma unroll
    for (int fi = 0; fi < 4; ++fi)
#pragma unroll
      for (int ks = 0; ks < 2; ++ks){
        unsigned oa = (unsigned)(((wr * 64 + fi * 16 + (l & 15)) << 7) + ks * 64 + ((l >> 4) << 4));
        afr[fi][ks] = *(const bf16x8*)((const char*)As + swz(oa));
        unsigned ob = (unsigned)(((wc * 64 + fi * 16 + (l & 15)) << 7) + ks * 64 + ((l >> 4) << 4));
        bfr[fi][ks] = *(const bf16x8*)((const char*)Bs + swz(ob));
      }
#pragma unroll
    for (int ks = 0; ks < 2; ++ks)
#pragma unroll
      for (int fi = 0; fi < 4; ++fi)
#pragma unroll
        for (int g = 0; g < 4; ++g)
          acc[fi][g] = __builtin_amdgcn_mfma_f32_16x16x32_bf16(
              afr[fi][ks], bfr[g][ks], acc[fi][g], 0, 0, 0);
    __syncthreads();                            // all waves done reading before restage
  }

  // epilogue
#pragma unroll
  for (int f = 0; f < 4; ++f){
    const int rowb = m0 + wr * 64 + f * 16 + ((l >> 4) << 2);
#pragma unroll
    for (int g = 0; g < 4; ++g){
      const int col = n0 + wc * 64 + g * 16 + (l & 15);
      const float bv = bias[col], gv = gate[col];
#pragma unroll
      for (int j = 0; j < 4; ++j){
        const int row = rowb + j;
        float v = acc[f][g][j] + bv;
        float gl = gelu_exact(v) * gv;
        if (MODE == 0){
          ((u16*)Cout)[(size_t)row * NDIM + col] = f2bf(gl);
        } else {
          size_t off = (size_t)row * NDIM + col;
          ((float*)Cout)[off] = xres[off] + gl;
        }
      }
    }
  }
}

// ---------------- launcher ----------------
extern "C" void kernel_launch(void* const* d_in, const int* in_sizes, int n_in,
                              void* d_out, int out_size, void* d_ws, size_t ws_size,
                              hipStream_t stream)
{
  const float* x       = (const float*)d_in[0];
  const int*   t       = (const int*)  d_in[1];
  const float* s       = (const float*)d_in[2];
  const float* fc1_w   = (const float*)d_in[3];
  const float* fc1_b   = (const float*)d_in[4];
  const float* fc2_w   = (const float*)d_in[5];
  const float* fc2_b   = (const float*)d_in[6];
  const float* efc1    = (const float*)d_in[7];
  const float* efc2    = (const float*)d_in[8];
  const float* sem_w   = (const float*)d_in[9];
  const float* sem_b   = (const float*)d_in[10];
  const float* rw      = (const float*)d_in[11];
  const float* larger_w= (const float*)d_in[12];
  const float* larger_b= (const float*)d_in[13];
  const float* elarger = (const float*)d_in[14];

  char* ws = (char*)d_ws;
  float* gfc1p   = (float*)(ws + 0);         //    8192 B  [2048]
  float* b1p     = (float*)(ws + 8192);      //    8192 B  [2048]
  float* gfc2    = (float*)(ws + 16384);     //    3072 B  [768]
  float* glarger = (float*)(ws + 19456);     //    3072 B  [768]
  u16*   Bw1     = (u16*)  (ws + 22528);     // 3145728 B  [2048][768] bf16
  u16*   Bw2     = (u16*)  (ws + 3168256);   // 3145728 B  [768][2048] bf16
  u16*   hpre    = (u16*)  (ws + 6313984);   // 25165824 B [16384][768] bf16
  u16*   Hm      = (u16*)  (ws + 31479808);  // 67108864 B [16384][2048] bf16
  // total 98,588,672 B

  prep_all<<<3080, 256, 0, stream>>>(s, t, efc1, efc2, elarger, fc1_b, fc1_w, fc2_w,
                                     gfc1p, b1p, gfc2, glarger, Bw1, Bw2);
  sem_route<<<512, 256, 0, stream>>>(x, t, sem_w, sem_b, rw, larger_w, larger_b, glarger, hpre);
  gemm128<0, 2048, 768><<<2048, 256, 0, stream>>>(hpre, Bw1, b1p, gfc1p, nullptr, (void*)Hm, 16);
  gemm128<1, 768, 2048><<<768, 256, 0, stream>>>(Hm, Bw2, fc2_b, gfc2, x, d_out, 6);
}